// Round 2
// baseline (355.364 us; speedup 1.0000x reference)
//
#include <hip/hip_runtime.h>

// B=16, C=512, N=4096 (64x64), CP=64.
// out = gamma*(wo@softmax((wk x)(wq x)^T)@(wv x)+bo)+x
// 5-kernel bf16-MFMA pipeline, no per-block weight staging, no LDS atomics:
//   k_prep:   one-shot fp32->bf16 of wq|wk|wv (fused [192][512]) and wo [512][64]
//   k_qkv:    W frags from global (L2-hot), x gathered per-lane -> q,k [cp][n], vt [n][cp]
//   k_energy: per-wave fp32 partials (64 splits), zero barriers
//   k_softmax: sum 64 partials + rowwise softmax -> attn bf16
//   k_avout:  attn*V (avl in LDS, swizzled) + wo-proj (global frags) + bias + gamma + residual

#define NN 4096
#define CIN 512
#define CPD 64

typedef short s8v __attribute__((ext_vector_type(8)));
typedef float f4v __attribute__((ext_vector_type(4)));
typedef unsigned short u16;

__device__ __forceinline__ u16 f2bf(float f) {
    union { float f; unsigned int u; } c; c.f = f;
    unsigned int r = c.u + 0x7FFFu + ((c.u >> 16) & 1u);   // RNE
    return (u16)(r >> 16);
}

// ---------------- K0: one-shot weight convert. 128 blocks x 256 thr, 4 elems/thr.
__global__ __launch_bounds__(256) void k_prep(
    const float* __restrict__ wq, const float* __restrict__ wk,
    const float* __restrict__ wv, const float* __restrict__ wo,
    u16* __restrict__ wqkvb, u16* __restrict__ wob)
{
    const int t = blockIdx.x * 256 + threadIdx.x;   // 32768 threads
    const int i4 = t * 4;
    const float* src; u16* dst; int off;
    if (i4 < 98304) {                // 3 * 64*512
        const int r = i4 >> 15;
        src = (r == 0) ? wq : (r == 1) ? wk : wv;
        off = i4 & 32767;
        dst = wqkvb + (r << 15);
    } else {
        src = wo; off = i4 - 98304; dst = wob;
    }
    float4 v = *(const float4*)(src + off);
    u16 tmp[4] = { f2bf(v.x), f2bf(v.y), f2bf(v.z), f2bf(v.w) };
    *(uint2*)(dst + off) = *(const uint2*)tmp;
}

// ---------------- K1: QKV. A = wqkv bf16 (global, L2-hot), B = x (per-lane gather).
// grid (32 nb, 16 b), block 256 (4 waves, each 32 n-cols). No LDS, no syncs.
// Output rows: o 0-63 = q, 64-127 = k, 128-191 = v.
__global__ __launch_bounds__(256, 2) void k_qkv(
    const float* __restrict__ x,
    const u16* __restrict__ wqkvb,
    const float* __restrict__ bq, const float* __restrict__ bk,
    const float* __restrict__ bv,
    u16* __restrict__ q, u16* __restrict__ k, u16* __restrict__ vt)
{
    const int nb = blockIdx.x, b = blockIdx.y;
    const int t = threadIdx.x;
    const int wv_ = t >> 6, L = t & 63, quad = L >> 4, l15 = L & 15;

    const int n_col0 = nb * 128 + wv_ * 32 + l15;
    const size_t xbase = (size_t)b * CIN * NN;

    f4v acc[12][2];
    #pragma unroll
    for (int ot = 0; ot < 12; ++ot)
        #pragma unroll
        for (int nn = 0; nn < 2; ++nn) acc[ot][nn] = (f4v){0.f,0.f,0.f,0.f};

    for (int ks = 0; ks < 16; ++ks) {       // K-steps of 32 c
        const int c = ks * 32 + quad * 8;
        // B fragments: gather x (lanes = consecutive n -> 64B segs, 4 c-rows/inst)
        float bx0[8], bx1[8];
        #pragma unroll
        for (int j = 0; j < 8; ++j) {
            const float* xc = x + xbase + (size_t)(c + j) * NN + n_col0;
            bx0[j] = xc[0];
            bx1[j] = xc[16];
        }
        s8v bf0, bf1;
        #pragma unroll
        for (int j = 0; j < 8; ++j) {
            bf0[j] = (short)f2bf(bx0[j]);
            bf1[j] = (short)f2bf(bx1[j]);
        }
        #pragma unroll
        for (int ot = 0; ot < 12; ++ot) {
            s8v af = *(const s8v*)(wqkvb + (ot * 16 + l15) * CIN + c);
            acc[ot][0] = __builtin_amdgcn_mfma_f32_16x16x32_bf16(
                af, bf0, acc[ot][0], 0, 0, 0);
            acc[ot][1] = __builtin_amdgcn_mfma_f32_16x16x32_bf16(
                af, bf1, acc[ot][1], 0, 0, 0);
        }
    }

    // epilogue: D rows o = ot*16+quad*4+r, cols n = n_col0 + nn*16
    #pragma unroll
    for (int p = 0; p < 2; ++p) {
        u16* outp = ((p == 0) ? q : k) + (size_t)b * CPD * NN;
        const float* bp = (p == 0) ? bq : bk;
        #pragma unroll
        for (int ot4 = 0; ot4 < 4; ++ot4) {
            float4 b4 = *(const float4*)(bp + ot4 * 16 + quad * 4);
            const float bsv[4] = { b4.x, b4.y, b4.z, b4.w };
            #pragma unroll
            for (int nn = 0; nn < 2; ++nn) {
                const int n = n_col0 + nn * 16;
                #pragma unroll
                for (int r = 0; r < 4; ++r) {
                    int o = ot4 * 16 + quad * 4 + r;
                    outp[(size_t)o * NN + n] =
                        f2bf(acc[p * 4 + ot4][nn][r] + bsv[r]);
                }
            }
        }
    }
    {
        u16* vtb = vt + (size_t)b * NN * CPD;
        #pragma unroll
        for (int ot4 = 0; ot4 < 4; ++ot4) {
            float4 b4 = *(const float4*)(bv + ot4 * 16 + quad * 4);
            const float bsv[4] = { b4.x, b4.y, b4.z, b4.w };
            #pragma unroll
            for (int nn = 0; nn < 2; ++nn) {
                const int n = n_col0 + nn * 16;
                u16 tmp[4];
                #pragma unroll
                for (int r = 0; r < 4; ++r)
                    tmp[r] = f2bf(acc[8 + ot4][nn][r] + bsv[r]);
                *(uint2*)(vtb + (size_t)n * CPD + ot4 * 16 + quad * 4) =
                    *(const uint2*)tmp;
            }
        }
    }
}

// ---------------- K2: energy partials. Each WAVE owns a 64-n chunk and writes
// its own fp32 partial (64 splits per batch). No LDS, no barriers, no atomics.
__global__ __launch_bounds__(256, 4) void k_energy(
    const u16* __restrict__ q, const u16* __restrict__ k,
    float* __restrict__ epart)   // [b][64][64][64] fp32
{
    const int s = blockIdx.x;   // 16 n-chunks of 256
    const int b = blockIdx.y;
    const int t = threadIdx.x;
    const int wv_ = t >> 6, L = t & 63, quad = L >> 4, l15 = L & 15;
    const u16* kb = k + (size_t)b * CPD * NN;
    const u16* qb = q + (size_t)b * CPD * NN;

    f4v acc[4][4];
    #pragma unroll
    for (int a = 0; a < 4; ++a)
        #pragma unroll
        for (int d = 0; d < 4; ++d) acc[a][d] = (f4v){0.f,0.f,0.f,0.f};

    const int nbase = s * 256 + wv_ * 64;
    #pragma unroll
    for (int ksl = 0; ksl < 2; ++ksl) {
        const int n = nbase + ksl * 32 + quad * 8;
        s8v af[4], bf_[4];
        #pragma unroll
        for (int it = 0; it < 4; ++it)
            af[it] = *(const s8v*)(kb + (size_t)(it * 16 + l15) * NN + n);
        #pragma unroll
        for (int jt = 0; jt < 4; ++jt)
            bf_[jt] = *(const s8v*)(qb + (size_t)(jt * 16 + l15) * NN + n);
        #pragma unroll
        for (int it = 0; it < 4; ++it)
            #pragma unroll
            for (int jt = 0; jt < 4; ++jt)
                acc[it][jt] = __builtin_amdgcn_mfma_f32_16x16x32_bf16(
                    af[it], bf_[jt], acc[it][jt], 0, 0, 0);
    }

    float* ep = epart + ((size_t)b * 64 + s * 4 + wv_) * 4096;
    #pragma unroll
    for (int it = 0; it < 4; ++it)
        #pragma unroll
        for (int jt = 0; jt < 4; ++jt)
            #pragma unroll
            for (int r = 0; r < 4; ++r)
                ep[(it * 16 + quad * 4 + r) * 64 + jt * 16 + l15] =
                    acc[it][jt][r];
}

// ---------------- K3: sum 64 partials + softmax over j -> attn bf16 [b][i][j]
__global__ __launch_bounds__(64) void k_softmax(
    const float* __restrict__ epart, u16* __restrict__ attn)
{
    const int i = blockIdx.x;
    const int b = blockIdx.y;
    const int j = threadIdx.x;
    float s = 0.f;
    #pragma unroll
    for (int sp = 0; sp < 64; ++sp)
        s += epart[((size_t)b * 64 + sp) * 4096 + i * 64 + j];
    float m = s;
    #pragma unroll
    for (int off = 32; off; off >>= 1) m = fmaxf(m, __shfl_xor(m, off));
    float e = __expf(s - m);
    float tot = e;
    #pragma unroll
    for (int off = 32; off; off >>= 1) tot += __shfl_xor(tot, off);
    attn[(size_t)b * 4096 + i * 64 + j] = f2bf(e / tot);
}

// ---------------- K4: fused attn*V + out-proj + residual.
// grid (32 nb, 16 b), block 256 (4 waves, each 32 n). n-tile 128.
// phase1: D1[i][n] = attn x vt -> avl LDS [n][i] (swizzled). 16 KB LDS only.
// phase2: D2[n][c] = avl x wob (global B-frags) -> float4 epilogue along n.
__global__ __launch_bounds__(256, 4) void k_avout(
    const u16* __restrict__ vt, const u16* __restrict__ attn,
    const u16* __restrict__ wob, const float* __restrict__ bo,
    const float* __restrict__ gamma, const float* __restrict__ x,
    float* __restrict__ out)
{
    const int nb = blockIdx.x, b = blockIdx.y;
    const int t = threadIdx.x;
    const int wv_ = t >> 6, L = t & 63, quad = L >> 4, l15 = L & 15;
    const int swz = (l15 & 7) * 8;

    __shared__ u16 avl[128 * 64];   // [n][i], swizzled, 16 KB

    // phase 1: avt tile (128 n-cols), A = attn (global), B = vt (global)
    {
        const u16* ab  = attn + (size_t)b * 4096;
        const u16* vtb = vt + (size_t)b * NN * CPD;
        const int n0 = nb * 128;
        f4v acc1[4][2];   // [it][ntc]
        #pragma unroll
        for (int a = 0; a < 4; ++a)
            #pragma unroll
            for (int d = 0; d < 2; ++d) acc1[a][d] = (f4v){0.f,0.f,0.f,0.f};
        #pragma unroll
        for (int ks = 0; ks < 2; ++ks) {
            const int j = ks * 32 + quad * 8;
            s8v af[4], bf_[2];
            #pragma unroll
            for (int it = 0; it < 4; ++it)
                af[it] = *(const s8v*)(ab + (size_t)(it * 16 + l15) * 64 + j);
            #pragma unroll
            for (int nn = 0; nn < 2; ++nn)
                bf_[nn] = *(const s8v*)(vtb +
                    (size_t)(n0 + wv_ * 32 + nn * 16 + l15) * CPD + j);
            #pragma unroll
            for (int it = 0; it < 4; ++it)
                #pragma unroll
                for (int nn = 0; nn < 2; ++nn)
                    acc1[it][nn] = __builtin_amdgcn_mfma_f32_16x16x32_bf16(
                        af[it], bf_[nn], acc1[it][nn], 0, 0, 0);
        }
        #pragma unroll
        for (int it = 0; it < 4; ++it)
            #pragma unroll
            for (int nn = 0; nn < 2; ++nn) {
                const int nloc = wv_ * 32 + nn * 16 + l15;
                u16 tmp[4];
                #pragma unroll
                for (int r = 0; r < 4; ++r) tmp[r] = f2bf(acc1[it][nn][r]);
                *(uint2*)&avl[nloc * 64 + ((it * 16 + quad * 4) ^ swz)] =
                    *(const uint2*)tmp;
            }
    }
    __syncthreads();

    // phase 2: out = gamma*(wo@av + bo) + x, float4 along n
    const float g = gamma[0];
    const int n0 = nb * 128;
    for (int cb = 0; cb < 8; ++cb) {
        f4v acc2[2][4];   // [nt][ct]
        #pragma unroll
        for (int a = 0; a < 2; ++a)
            #pragma unroll
            for (int d = 0; d < 4; ++d) acc2[a][d] = (f4v){0.f,0.f,0.f,0.f};
        #pragma unroll
        for (int ks = 0; ks < 2; ++ks) {
            const int i0 = ks * 32 + quad * 8;
            const int ic = i0 ^ swz;
            s8v af2[2], bf2[4];
            #pragma unroll
            for (int nt = 0; nt < 2; ++nt)
                af2[nt] = *(const s8v*)&avl[(wv_ * 32 + nt * 16 + l15) * 64 + ic];
            #pragma unroll
            for (int ct = 0; ct < 4; ++ct)
                bf2[ct] = *(const s8v*)(wob +
                    (size_t)(cb * 64 + ct * 16 + l15) * CPD + i0);
            #pragma unroll
            for (int nt = 0; nt < 2; ++nt)
                #pragma unroll
                for (int ct = 0; ct < 4; ++ct)
                    acc2[nt][ct] = __builtin_amdgcn_mfma_f32_16x16x32_bf16(
                        af2[nt], bf2[ct], acc2[nt][ct], 0, 0, 0);
        }
        // D2 rows n = n0+wv_*32+nt*16+quad*4+r, cols c = cb*64+ct*16+l15
        #pragma unroll
        for (int nt = 0; nt < 2; ++nt)
            #pragma unroll
            for (int ct = 0; ct < 4; ++ct) {
                const int c = cb * 64 + ct * 16 + l15;
                const float bs = bo[c];
                const int nbase = n0 + wv_ * 32 + nt * 16 + quad * 4;
                const size_t idx = ((size_t)b * CIN + c) * NN + nbase;
                float4 xr = *(const float4*)(x + idx);
                float4 r4;
                r4.x = g * (acc2[nt][ct][0] + bs) + xr.x;
                r4.y = g * (acc2[nt][ct][1] + bs) + xr.y;
                r4.z = g * (acc2[nt][ct][2] + bs) + xr.z;
                r4.w = g * (acc2[nt][ct][3] + bs) + xr.w;
                *(float4*)(out + idx) = r4;
            }
    }
}

extern "C" void kernel_launch(void* const* d_in, const int* in_sizes, int n_in,
                              void* d_out, int out_size, void* d_ws, size_t ws_size,
                              hipStream_t stream) {
    const float* x  = (const float*)d_in[0];
    const float* wq = (const float*)d_in[1];
    const float* bq = (const float*)d_in[2];
    const float* wk = (const float*)d_in[3];
    const float* bk = (const float*)d_in[4];
    const float* wv = (const float*)d_in[5];
    const float* bv = (const float*)d_in[6];
    const float* wo = (const float*)d_in[7];
    const float* bo = (const float*)d_in[8];
    const float* gm = (const float*)d_in[9];
    float* out = (float*)d_out;

    // workspace (bytes), total ~40.4 MB:
    char* wsb = (char*)d_ws;
    u16*   q     = (u16*)wsb;                         //  8.39 MB [b][cp][n]
    u16*   k     = (u16*)(wsb + 8388608);             //  8.39 MB [b][cp][n]
    u16*   vt    = (u16*)(wsb + 16777216);            //  8.39 MB [b][n][cp]
    float* epart = (float*)(wsb + 25165824);          // 16.78 MB [b][64][64][64]
    u16*   attn  = (u16*)(wsb + 41943040);            //  0.13 MB [b][64][64]
    u16*   wqkvb = (u16*)(wsb + 42074112);            //  0.20 MB [192][512]
    u16*   wob   = (u16*)(wsb + 42270720);            //  0.06 MB [512][64]

    k_prep<<<128, 256, 0, stream>>>(wq, wk, wv, wo, wqkvb, wob);
    k_qkv<<<dim3(32, 16), 256, 0, stream>>>(x, wqkvb, bq, bk, bv, q, k, vt);
    k_energy<<<dim3(16, 16), 256, 0, stream>>>(q, k, epart);
    k_softmax<<<dim3(64, 16), 64, 0, stream>>>(epart, attn);
    k_avout<<<dim3(32, 16), 256, 0, stream>>>(vt, attn, wob, bo, gm, x, out);
}